// Round 10
// baseline (287.306 us; speedup 1.0000x reference)
//
#include <hip/hip_runtime.h>
#include <hip/hip_bf16.h>
#include <math.h>

// IntentionHeads R18 = R16 compute structure + token compaction (4x less work).
//   R17 post-mortem: (512,8) = 64-reg cap; kernel needs 72 -> spill
//   (WRITE 86MB), 115us. Occupancy curve now mapped: 8/16/24 waves/CU
//   monotone better, 32 only via spill = net loss. R16 (99.4us) is the
//   optimum of the compute-everything structure.
// R18 algorithmic change: ids are ~25% vehicle / ~25% ped / ~50% neither.
//   Old kernel ran 131072 token-head units; only ~32768 are needed.
//   - compact_kernel: wave ballot + 1 atomicAdd/wave -> idxV/idxP lists in
//     ws; writes both masks; zero-fills all 6 logit slots (covers types
//     0/3 and ped cols 2-5). Order nondeterminism is benign: each token's
//     values are independent of tile-mates (MFMA rows independent, K-order
//     per token unchanged) -> outputs bit-identical, absmax 0.015625.
//   - main kernel: verbatim R16 (512thr, 8 thin waves, frag-B, fast erf,
//     lgkm BAR, (512,6) no-spill) but processes 64 COMPACTED tokens of one
//     head via indexed X rows; scatter-writes its own logits only; blocks
//     past count exit immediately. Row gather keeps 128B-segment
//     coalescing (rows scattered, segments intact).
//   ws: Wc 512KB ++ W2c 16KB ++ cnt[2] ++ idxV/idxP (2x256KB) ~= 1.04MB.

#define TOKENS 65536
#define DIM    512
#define HID    256
#define ASTR   40    // X staging row stride in bf16 (32 + 8 pad, 16B mult)
#define HSTR   264   // H row stride in bf16 (256 + 8 pad, 16B mult)

using short8 = __attribute__((ext_vector_type(8))) short;  // 8 x bf16
using f32x4  = __attribute__((ext_vector_type(4))) float;

// lgkm-only barrier: LDS producer/consumer ordering WITHOUT draining vmcnt
// (no global->LDS traffic exists; global loads are register-only).
#define BAR()                                                      \
    do {                                                           \
        __builtin_amdgcn_sched_barrier(0);                         \
        asm volatile("s_waitcnt lgkmcnt(0)" ::: "memory");         \
        __builtin_amdgcn_s_barrier();                              \
        __builtin_amdgcn_sched_barrier(0);                         \
    } while (0)

// packed RNE f32->bf16 pair (v_perm byte-pack)
__device__ __forceinline__ unsigned int pkrne(float a, float b) {
    unsigned int ua = __float_as_uint(a);
    unsigned int ub = __float_as_uint(b);
    ua += 0x7FFFu + ((ua >> 16) & 1u);
    ub += 0x7FFFu + ((ub >> 16) & 1u);
    return __builtin_amdgcn_perm(ub, ua, 0x07060302u);  // [ua.hi16, ub.hi16]
}

__device__ __forceinline__ uint2 cvt4(f32x4 v) {
    return make_uint2(pkrne(v[0], v[1]), pkrne(v[2], v[3]));
}

__device__ __forceinline__ __hip_bfloat16 bf16rne(float x) {
    unsigned int u = __float_as_uint(x);
    u += 0x7FFFu + ((u >> 16) & 1u);
    unsigned short hs = (unsigned short)(u >> 16);
    return *(__hip_bfloat16*)&hs;
}

__device__ __forceinline__ float gelu_exact(float x) {
    // exact-GELU via branch-free A&S 7.1.26 erf, |abs err| <= 1.5e-7
    // (far below one bf16 ulp of H -> output bits unchanged vs libm).
    const float z  = fabsf(x) * 0.7071067811865475f;
    const float t  = __builtin_amdgcn_rcpf(fmaf(0.3275911f, z, 1.0f));
    float p = fmaf(1.061405429f, t, -1.453152027f);
    p = fmaf(p, t, 1.421413741f);
    p = fmaf(p, t, -0.284496736f);
    p = fmaf(p, t, 0.254829592f);
    p = p * t;
    const float e  = __expf(-z * z);           // v_exp_f32 path
    const float er = fmaf(-p, e, 1.0f);        // erf(|z|) >= 0
    return 0.5f * x * (1.0f + copysignf(er, x));
}

// ---------------- prep: weights -> fragment-contiguous bf16 -----------------
// Wc  (512KB): 16B chunk c = ((nt*16 + it)*64 + lane), nt = head*16 + n/16,
//   lane = quad*16+l16 -> W1[head][ (nt&15)*16 + l16 ][ it*32 + quad*8 ..+7 ]
// W2c (16KB): chunk c = (ks*2+head)*64 + lane ->
//   W2[head][l16][ks*32 + quad*8 ..+7], zero when l16 >= nOut.
__global__ __launch_bounds__(256)
void prep_kernel(const float* __restrict__ vW1, const float* __restrict__ pW1,
                 const float* __restrict__ vW2, const float* __restrict__ pW2,
                 __hip_bfloat16* __restrict__ Wc, __hip_bfloat16* __restrict__ W2c,
                 int* __restrict__ cnt)
{
    const int i = blockIdx.x * 256 + threadIdx.x;   // 16B chunk index
    if (i < 2) cnt[i] = 0;                          // zero compaction counters
    if (i < 32768) {                                // W1: 512x512 bf16
        const int lane = i & 63;
        const int it   = (i >> 6) & 15;
        const int nt   = i >> 10;                   // 0..31
        const int head = nt >> 4;
        const int row  = (nt & 15) * 16 + (lane & 15);
        const int k    = it * 32 + (lane >> 4) * 8;
        const float* src = (head ? pW1 : vW1) + row * DIM + k;
        f32x4 a = *(const f32x4*)(src);
        f32x4 b = *(const f32x4*)(src + 4);
        uint2 lo = cvt4(a), hi = cvt4(b);
        *(uint4*)((char*)Wc + (long)i * 16) = make_uint4(lo.x, lo.y, hi.x, hi.y);
    } else if (i < 32768 + 1024) {                  // W2c: 16KB
        const int c    = i - 32768;
        const int lane = c & 63;
        const int rest = c >> 6;                    // 0..15
        const int head = rest & 1;
        const int ks   = rest >> 1;                 // 0..7
        const int l16  = lane & 15;
        const int quad = lane >> 4;
        const int nOut = head ? 2 : 6;
        uint4 o = make_uint4(0u, 0u, 0u, 0u);
        if (l16 < nOut) {
            const float* src = (head ? pW2 : vW2) + l16 * HID + ks * 32 + quad * 8;
            f32x4 a = *(const f32x4*)(src);
            f32x4 b = *(const f32x4*)(src + 4);
            uint2 lo = cvt4(a), hi = cvt4(b);
            o = make_uint4(lo.x, lo.y, hi.x, hi.y);
        }
        *(uint4*)((char*)W2c + (long)c * 16) = o;
    }
}

// ---------------- compact: masks + zero-fill + per-type token lists ---------
__global__ __launch_bounds__(256)
void compact_kernel(const int* __restrict__ ids, float* __restrict__ out,
                    int* __restrict__ cnt,
                    int* __restrict__ idxV, int* __restrict__ idxP)
{
    const int i = blockIdx.x * 256 + threadIdx.x;   // token, grid covers 65536
    const int type = ids[i];
    out[TOKENS * 6 + i] = (type == 1) ? 1.0f : 0.0f;
    out[TOKENS * 7 + i] = (type == 2) ? 1.0f : 0.0f;
    // zero all 6 logit slots (3 x 8B stores; 24B stride is 8B-aligned)
    uint2 z = make_uint2(0u, 0u);
    uint2* p = (uint2*)(out + (long)i * 6);
    p[0] = z; p[1] = z; p[2] = z;

    const int lane = threadIdx.x & 63;
    const unsigned long long below = (lane == 63) ? ~0ull >> 1
                                   : (1ull << lane) - 1ull;
    {
        unsigned long long m = __ballot(type == 1);
        if (m) {
            const int leader = __ffsll((long long)m) - 1;
            int base = 0;
            if (lane == leader) base = atomicAdd(cnt + 0, __popcll(m));
            base = __shfl(base, leader);
            if (type == 1) idxV[base + __popcll(m & below)] = i;
        }
    }
    {
        unsigned long long m = __ballot(type == 2);
        if (m) {
            const int leader = __ffsll((long long)m) - 1;
            int base = 0;
            if (lane == leader) base = atomicAdd(cnt + 1, __popcll(m));
            base = __shfl(base, leader);
            if (type == 2) idxP[base + __popcll(m & below)] = i;
        }
    }
}

// ---------------- main ------------------------------------------------------
__global__ __launch_bounds__(512, 6)
void intention_heads_kernel(const float* __restrict__ X,
                            const int* __restrict__ cnt,
                            const int* __restrict__ idxV,
                            const int* __restrict__ idxP,
                            const __hip_bfloat16* __restrict__ Wc,
                            const __hip_bfloat16* __restrict__ W2c,
                            const float* __restrict__ vb1,
                            const float* __restrict__ pb1,
                            const float* __restrict__ vb2,
                            const float* __restrict__ pb2,
                            float* __restrict__ out)
{
    // LDS union: X staging A0/A1 (2 x 64x40 bf16 = 10.2KB) then H
    // 64x264 bf16 (33.8KB).
    __shared__ __align__(16) unsigned char smem[64 * HSTR * 2];
    __hip_bfloat16* H = (__hip_bfloat16*)smem;

    // XCD swizzle (harmless with gather; keeps early-exit blocks spread)
    const int cpx = gridDim.x >> 3;
    const int bid = (blockIdx.x & 7) * cpx + (blockIdx.x >> 3);

    const int head = bid & 1;           // 0 = vehicle, 1 = pedestrian
    const int tile = bid >> 1;
    const int count = cnt[head];
    if (tile * 64 >= count) return;     // no tokens for this block
    const int* __restrict__ idx = head ? idxP : idxV;
    const int base = tile * 64;

    const int tid  = threadIdx.x;
    const int wave = tid >> 6;          // 0..7 -> cols wave*32
    const int lane = tid & 63;
    const int quad = lane >> 4;
    const int l16  = lane & 15;
    const int wcol = wave * 32;

    // X staging: thread owns ONE f32x4 of slot-row r (compacted token)
    const int q = tid & 7;
    const int r = tid >> 3;             // 0..63 (slot within tile)
    const int slot  = base + r;
    const int tok   = idx[(slot < count) ? slot : (count - 1)];
    const float* Xs = X + (long)tok * DIM + q * 4;

    // B frags, fragment-contiguous: wave's (j,it) chunk = contiguous 1KB.
    const char* Bq = (const char*)Wc
                   + (long)(head * 16 + wave * 2) * 16384 + (long)lane * 16;

    f32x4 acc[4][2];
    #pragma unroll
    for (int i = 0; i < 4; ++i)
        #pragma unroll
        for (int j = 0; j < 2; ++j)
            acc[i][j] = (f32x4){0.f, 0.f, 0.f, 0.f};

    // ---- prologue: stage tile 0 ----
    f32x4 ga = *(const f32x4*)(Xs);
    {
        __hip_bfloat16* A = (__hip_bfloat16*)smem;   // buffer 0
        *(uint2*)&A[r * ASTR + q * 4] = cvt4(ga);
    }
    BAR();

    // ---- K loop: 16 iters, BK=32, double buffer, depth-1 prefetch ----
    #pragma unroll
    for (int it = 0; it < DIM / 32; ++it) {
        __hip_bfloat16* cur = (__hip_bfloat16*)(smem + (it & 1) * 5120);
        __hip_bfloat16* nxt = (__hip_bfloat16*)(smem + ((it + 1) & 1) * 5120);

        // issue tile it+1 raw load (consumed at this iter's bottom)
        if (it < 15)
            ga = *(const f32x4*)(Xs + (it + 1) * 32);

        // this iter's B frags: 2 contiguous 1KB wave-reads (8 full lines ea)
        short8 bc[2];
        #pragma unroll
        for (int j = 0; j < 2; ++j)
            bc[j] = *(const short8*)(Bq + j * 16384 + it * 1024);

        short8 af[4];
        #pragma unroll
        for (int i = 0; i < 4; ++i)
            af[i] = *(const short8*)&cur[(i * 16 + l16) * ASTR + quad * 8];

        #pragma unroll
        for (int i = 0; i < 4; ++i)
            #pragma unroll
            for (int j = 0; j < 2; ++j)
                acc[i][j] = __builtin_amdgcn_mfma_f32_16x16x32_bf16(af[i], bc[j], acc[i][j], 0, 0, 0);

        // convert+stage tile it+1
        if (it < 15)
            *(uint2*)&nxt[r * ASTR + q * 4] = cvt4(ga);
        BAR();
    }

    // ------------- bias + GELU, stage H tile (bf16) -----------------------
    const float* b1 = head ? pb1 : vb1;
    float b1v[2];
    #pragma unroll
    for (int j = 0; j < 2; ++j)
        b1v[j] = b1[wcol + j * 16 + l16];

    #pragma unroll
    for (int i = 0; i < 4; ++i) {
        #pragma unroll
        for (int j = 0; j < 2; ++j) {
            const int col = wcol + j * 16 + l16;
            #pragma unroll
            for (int rr = 0; rr < 4; ++rr) {
                const int row = i * 16 + quad * 4 + rr;
                H[row * HSTR + col] = bf16rne(gelu_exact(acc[i][j][rr] + b1v[j]));
            }
        }
    }
    BAR();

    // ------------- layer 2 (waves 0-3): H[64x256] @ W2^T ------------------
    if (wave < 4) {
        const float* b2 = head ? pb2 : vb2;
        const int nOut = head ? 2 : 6;

        f32x4 acc2 = (f32x4){0.f, 0.f, 0.f, 0.f};
        const int tokb = wave * 16;
        const short* hbase = (const short*)&H[(tokb + l16) * HSTR + quad * 8];
        const char*  w2q   = (const char*)W2c + head * 1024 + (long)lane * 16;
        #pragma unroll
        for (int ks = 0; ks < 8; ++ks) {
            short8 af    = *(const short8*)(hbase + ks * 32);
            short8 bfrag = *(const short8*)(w2q + ks * 2048);  // zero-padded
            acc2 = __builtin_amdgcn_mfma_f32_16x16x32_bf16(af, bfrag, acc2, 0, 0, 0);
        }

        // ------------- scatter epilogue (own head only) -------------------
        const float b2v = (l16 < nOut) ? b2[l16] : 0.0f;

        #pragma unroll
        for (int rr = 0; rr < 4; ++rr) {
            const int s = base + tokb + quad * 4 + rr;
            if (s < count && l16 < nOut) {
                const int t = idx[s];
                out[t * 6 + l16] = acc2[rr] + b2v;
            }
        }
    }
}

extern "C" void kernel_launch(void* const* d_in, const int* in_sizes, int n_in,
                              void* d_out, int out_size, void* d_ws, size_t ws_size,
                              hipStream_t stream) {
    (void)n_in; (void)out_size; (void)ws_size;
    const float* X   = (const float*)d_in[0];
    const int*   ids = (const int*)d_in[1];
    const float* vW1 = (const float*)d_in[2];
    const float* vb1 = (const float*)d_in[3];
    const float* vW2 = (const float*)d_in[4];
    const float* vb2 = (const float*)d_in[5];
    const float* pW1 = (const float*)d_in[6];
    const float* pb1 = (const float*)d_in[7];
    const float* pW2 = (const float*)d_in[8];
    const float* pb2 = (const float*)d_in[9];
    float* out = (float*)d_out;

    // workspace: Wc 512KB ++ W2c 16KB ++ cnt[2] (256B slot) ++ idxV ++ idxP
    char* ws = (char*)d_ws;
    __hip_bfloat16* Wc  = (__hip_bfloat16*)ws;
    __hip_bfloat16* W2c = (__hip_bfloat16*)(ws + 512 * 1024);
    int* cnt  = (int*)(ws + 512 * 1024 + 16 * 1024);
    int* idxV = (int*)(ws + 512 * 1024 + 16 * 1024 + 256);
    int* idxP = idxV + TOKENS;

    hipLaunchKernelGGL(prep_kernel, dim3(132), dim3(256), 0, stream,
                       vW1, pW1, vW2, pW2, Wc, W2c, cnt);

    hipLaunchKernelGGL(compact_kernel, dim3(TOKENS / 256), dim3(256), 0, stream,
                       ids, out, cnt, idxV, idxP);

    // grid covers worst case (all tokens one type): 1024 tiles x 2 heads
    hipLaunchKernelGGL(intention_heads_kernel, dim3(2048), dim3(512), 0, stream,
                       X, cnt, idxV, idxP, Wc, W2c, vb1, pb1, vb2, pb2, out);
}

// Round 11
// 236.038 us; speedup vs baseline: 1.2172x; 1.2172x over previous
//
#include <hip/hip_runtime.h>
#include <hip/hip_bf16.h>
#include <math.h>

// IntentionHeads R19 = R18 minus the XCD swizzle (load-balance bug fix).
//   R18 post-mortem: compaction delivered exactly 4x less work (FETCH
//   70->35MB, conflicts 5.5M->1.38M) but dur ROSE 99.4->111us at 12%
//   occupancy. Cause: working blocks are bid < ~512, and the swizzle
//   bid=(blockIdx&7)*256+(blockIdx>>3) maps them to blockIdx%8 in {0,1}
//   -> ALL working blocks landed on 2 of 8 XCDs (64 CUs busy, 192 idle).
//   The swizzle that helped the dense kernel is wrong for a compacted
//   prefix working set.
// R19 change (single variable): bid = blockIdx.x. Working blocks 0..511
//   round-robin across all XCDs -> ~2 blocks/CU (16 waves/CU) steady
//   state. Predicted main ~= 99.4 x (1/4 work) x (24/16 waves) ~= 37us.
//   Everything else byte-identical to R18: compact ballot lists, R16
//   compute structure (512thr, 8 thin waves, frag-B, fast erf, lgkm BAR,
//   (512,6) no-spill), scatter epilogue, numerics (absmax 0.015625).

#define TOKENS 65536
#define DIM    512
#define HID    256
#define ASTR   40    // X staging row stride in bf16 (32 + 8 pad, 16B mult)
#define HSTR   264   // H row stride in bf16 (256 + 8 pad, 16B mult)

using short8 = __attribute__((ext_vector_type(8))) short;  // 8 x bf16
using f32x4  = __attribute__((ext_vector_type(4))) float;

// lgkm-only barrier: LDS producer/consumer ordering WITHOUT draining vmcnt
// (no global->LDS traffic exists; global loads are register-only).
#define BAR()                                                      \
    do {                                                           \
        __builtin_amdgcn_sched_barrier(0);                         \
        asm volatile("s_waitcnt lgkmcnt(0)" ::: "memory");         \
        __builtin_amdgcn_s_barrier();                              \
        __builtin_amdgcn_sched_barrier(0);                         \
    } while (0)

// packed RNE f32->bf16 pair (v_perm byte-pack)
__device__ __forceinline__ unsigned int pkrne(float a, float b) {
    unsigned int ua = __float_as_uint(a);
    unsigned int ub = __float_as_uint(b);
    ua += 0x7FFFu + ((ua >> 16) & 1u);
    ub += 0x7FFFu + ((ub >> 16) & 1u);
    return __builtin_amdgcn_perm(ub, ua, 0x07060302u);  // [ua.hi16, ub.hi16]
}

__device__ __forceinline__ uint2 cvt4(f32x4 v) {
    return make_uint2(pkrne(v[0], v[1]), pkrne(v[2], v[3]));
}

__device__ __forceinline__ __hip_bfloat16 bf16rne(float x) {
    unsigned int u = __float_as_uint(x);
    u += 0x7FFFu + ((u >> 16) & 1u);
    unsigned short hs = (unsigned short)(u >> 16);
    return *(__hip_bfloat16*)&hs;
}

__device__ __forceinline__ float gelu_exact(float x) {
    // exact-GELU via branch-free A&S 7.1.26 erf, |abs err| <= 1.5e-7
    // (far below one bf16 ulp of H -> output bits unchanged vs libm).
    const float z  = fabsf(x) * 0.7071067811865475f;
    const float t  = __builtin_amdgcn_rcpf(fmaf(0.3275911f, z, 1.0f));
    float p = fmaf(1.061405429f, t, -1.453152027f);
    p = fmaf(p, t, 1.421413741f);
    p = fmaf(p, t, -0.284496736f);
    p = fmaf(p, t, 0.254829592f);
    p = p * t;
    const float e  = __expf(-z * z);           // v_exp_f32 path
    const float er = fmaf(-p, e, 1.0f);        // erf(|z|) >= 0
    return 0.5f * x * (1.0f + copysignf(er, x));
}

// ---------------- prep: weights -> fragment-contiguous bf16 -----------------
// Wc  (512KB): 16B chunk c = ((nt*16 + it)*64 + lane), nt = head*16 + n/16,
//   lane = quad*16+l16 -> W1[head][ (nt&15)*16 + l16 ][ it*32 + quad*8 ..+7 ]
// W2c (16KB): chunk c = (ks*2+head)*64 + lane ->
//   W2[head][l16][ks*32 + quad*8 ..+7], zero when l16 >= nOut.
__global__ __launch_bounds__(256)
void prep_kernel(const float* __restrict__ vW1, const float* __restrict__ pW1,
                 const float* __restrict__ vW2, const float* __restrict__ pW2,
                 __hip_bfloat16* __restrict__ Wc, __hip_bfloat16* __restrict__ W2c,
                 int* __restrict__ cnt)
{
    const int i = blockIdx.x * 256 + threadIdx.x;   // 16B chunk index
    if (i < 2) cnt[i] = 0;                          // zero compaction counters
    if (i < 32768) {                                // W1: 512x512 bf16
        const int lane = i & 63;
        const int it   = (i >> 6) & 15;
        const int nt   = i >> 10;                   // 0..31
        const int head = nt >> 4;
        const int row  = (nt & 15) * 16 + (lane & 15);
        const int k    = it * 32 + (lane >> 4) * 8;
        const float* src = (head ? pW1 : vW1) + row * DIM + k;
        f32x4 a = *(const f32x4*)(src);
        f32x4 b = *(const f32x4*)(src + 4);
        uint2 lo = cvt4(a), hi = cvt4(b);
        *(uint4*)((char*)Wc + (long)i * 16) = make_uint4(lo.x, lo.y, hi.x, hi.y);
    } else if (i < 32768 + 1024) {                  // W2c: 16KB
        const int c    = i - 32768;
        const int lane = c & 63;
        const int rest = c >> 6;                    // 0..15
        const int head = rest & 1;
        const int ks   = rest >> 1;                 // 0..7
        const int l16  = lane & 15;
        const int quad = lane >> 4;
        const int nOut = head ? 2 : 6;
        uint4 o = make_uint4(0u, 0u, 0u, 0u);
        if (l16 < nOut) {
            const float* src = (head ? pW2 : vW2) + l16 * HID + ks * 32 + quad * 8;
            f32x4 a = *(const f32x4*)(src);
            f32x4 b = *(const f32x4*)(src + 4);
            uint2 lo = cvt4(a), hi = cvt4(b);
            o = make_uint4(lo.x, lo.y, hi.x, hi.y);
        }
        *(uint4*)((char*)W2c + (long)c * 16) = o;
    }
}

// ---------------- compact: masks + zero-fill + per-type token lists ---------
__global__ __launch_bounds__(256)
void compact_kernel(const int* __restrict__ ids, float* __restrict__ out,
                    int* __restrict__ cnt,
                    int* __restrict__ idxV, int* __restrict__ idxP)
{
    const int i = blockIdx.x * 256 + threadIdx.x;   // token, grid covers 65536
    const int type = ids[i];
    out[TOKENS * 6 + i] = (type == 1) ? 1.0f : 0.0f;
    out[TOKENS * 7 + i] = (type == 2) ? 1.0f : 0.0f;
    // zero all 6 logit slots (3 x 8B stores; 24B stride is 8B-aligned)
    uint2 z = make_uint2(0u, 0u);
    uint2* p = (uint2*)(out + (long)i * 6);
    p[0] = z; p[1] = z; p[2] = z;

    const int lane = threadIdx.x & 63;
    const unsigned long long below = (lane == 63) ? ~0ull >> 1
                                   : (1ull << lane) - 1ull;
    {
        unsigned long long m = __ballot(type == 1);
        if (m) {
            const int leader = __ffsll((long long)m) - 1;
            int base = 0;
            if (lane == leader) base = atomicAdd(cnt + 0, __popcll(m));
            base = __shfl(base, leader);
            if (type == 1) idxV[base + __popcll(m & below)] = i;
        }
    }
    {
        unsigned long long m = __ballot(type == 2);
        if (m) {
            const int leader = __ffsll((long long)m) - 1;
            int base = 0;
            if (lane == leader) base = atomicAdd(cnt + 1, __popcll(m));
            base = __shfl(base, leader);
            if (type == 2) idxP[base + __popcll(m & below)] = i;
        }
    }
}

// ---------------- main ------------------------------------------------------
__global__ __launch_bounds__(512, 6)
void intention_heads_kernel(const float* __restrict__ X,
                            const int* __restrict__ cnt,
                            const int* __restrict__ idxV,
                            const int* __restrict__ idxP,
                            const __hip_bfloat16* __restrict__ Wc,
                            const __hip_bfloat16* __restrict__ W2c,
                            const float* __restrict__ vb1,
                            const float* __restrict__ pb1,
                            const float* __restrict__ vb2,
                            const float* __restrict__ pb2,
                            float* __restrict__ out)
{
    // LDS union: X staging A0/A1 (2 x 64x40 bf16 = 10.2KB) then H
    // 64x264 bf16 (33.8KB).
    __shared__ __align__(16) unsigned char smem[64 * HSTR * 2];
    __hip_bfloat16* H = (__hip_bfloat16*)smem;

    // NO XCD swizzle: working blocks (low bids) must round-robin across
    // XCDs via native dispatch (R18 bug: swizzle piled them on 2 XCDs).
    const int bid = blockIdx.x;

    const int head = bid & 1;           // 0 = vehicle, 1 = pedestrian
    const int tile = bid >> 1;
    const int count = cnt[head];
    if (tile * 64 >= count) return;     // no tokens for this block
    const int* __restrict__ idx = head ? idxP : idxV;
    const int base = tile * 64;

    const int tid  = threadIdx.x;
    const int wave = tid >> 6;          // 0..7 -> cols wave*32
    const int lane = tid & 63;
    const int quad = lane >> 4;
    const int l16  = lane & 15;
    const int wcol = wave * 32;

    // X staging: thread owns ONE f32x4 of slot-row r (compacted token)
    const int q = tid & 7;
    const int r = tid >> 3;             // 0..63 (slot within tile)
    const int slot  = base + r;
    const int tok   = idx[(slot < count) ? slot : (count - 1)];
    const float* Xs = X + (long)tok * DIM + q * 4;

    // B frags, fragment-contiguous: wave's (j,it) chunk = contiguous 1KB.
    const char* Bq = (const char*)Wc
                   + (long)(head * 16 + wave * 2) * 16384 + (long)lane * 16;

    f32x4 acc[4][2];
    #pragma unroll
    for (int i = 0; i < 4; ++i)
        #pragma unroll
        for (int j = 0; j < 2; ++j)
            acc[i][j] = (f32x4){0.f, 0.f, 0.f, 0.f};

    // ---- prologue: stage tile 0 ----
    f32x4 ga = *(const f32x4*)(Xs);
    {
        __hip_bfloat16* A = (__hip_bfloat16*)smem;   // buffer 0
        *(uint2*)&A[r * ASTR + q * 4] = cvt4(ga);
    }
    BAR();

    // ---- K loop: 16 iters, BK=32, double buffer, depth-1 prefetch ----
    #pragma unroll
    for (int it = 0; it < DIM / 32; ++it) {
        __hip_bfloat16* cur = (__hip_bfloat16*)(smem + (it & 1) * 5120);
        __hip_bfloat16* nxt = (__hip_bfloat16*)(smem + ((it + 1) & 1) * 5120);

        // issue tile it+1 raw load (consumed at this iter's bottom)
        if (it < 15)
            ga = *(const f32x4*)(Xs + (it + 1) * 32);

        // this iter's B frags: 2 contiguous 1KB wave-reads (8 full lines ea)
        short8 bc[2];
        #pragma unroll
        for (int j = 0; j < 2; ++j)
            bc[j] = *(const short8*)(Bq + j * 16384 + it * 1024);

        short8 af[4];
        #pragma unroll
        for (int i = 0; i < 4; ++i)
            af[i] = *(const short8*)&cur[(i * 16 + l16) * ASTR + quad * 8];

        #pragma unroll
        for (int i = 0; i < 4; ++i)
            #pragma unroll
            for (int j = 0; j < 2; ++j)
                acc[i][j] = __builtin_amdgcn_mfma_f32_16x16x32_bf16(af[i], bc[j], acc[i][j], 0, 0, 0);

        // convert+stage tile it+1
        if (it < 15)
            *(uint2*)&nxt[r * ASTR + q * 4] = cvt4(ga);
        BAR();
    }

    // ------------- bias + GELU, stage H tile (bf16) -----------------------
    const float* b1 = head ? pb1 : vb1;
    float b1v[2];
    #pragma unroll
    for (int j = 0; j < 2; ++j)
        b1v[j] = b1[wcol + j * 16 + l16];

    #pragma unroll
    for (int i = 0; i < 4; ++i) {
        #pragma unroll
        for (int j = 0; j < 2; ++j) {
            const int col = wcol + j * 16 + l16;
            #pragma unroll
            for (int rr = 0; rr < 4; ++rr) {
                const int row = i * 16 + quad * 4 + rr;
                H[row * HSTR + col] = bf16rne(gelu_exact(acc[i][j][rr] + b1v[j]));
            }
        }
    }
    BAR();

    // ------------- layer 2 (waves 0-3): H[64x256] @ W2^T ------------------
    if (wave < 4) {
        const float* b2 = head ? pb2 : vb2;
        const int nOut = head ? 2 : 6;

        f32x4 acc2 = (f32x4){0.f, 0.f, 0.f, 0.f};
        const int tokb = wave * 16;
        const short* hbase = (const short*)&H[(tokb + l16) * HSTR + quad * 8];
        const char*  w2q   = (const char*)W2c + head * 1024 + (long)lane * 16;
        #pragma unroll
        for (int ks = 0; ks < 8; ++ks) {
            short8 af    = *(const short8*)(hbase + ks * 32);
            short8 bfrag = *(const short8*)(w2q + ks * 2048);  // zero-padded
            acc2 = __builtin_amdgcn_mfma_f32_16x16x32_bf16(af, bfrag, acc2, 0, 0, 0);
        }

        // ------------- scatter epilogue (own head only) -------------------
        const float b2v = (l16 < nOut) ? b2[l16] : 0.0f;

        #pragma unroll
        for (int rr = 0; rr < 4; ++rr) {
            const int s = base + tokb + quad * 4 + rr;
            if (s < count && l16 < nOut) {
                const int t = idx[s];
                out[t * 6 + l16] = acc2[rr] + b2v;
            }
        }
    }
}

extern "C" void kernel_launch(void* const* d_in, const int* in_sizes, int n_in,
                              void* d_out, int out_size, void* d_ws, size_t ws_size,
                              hipStream_t stream) {
    (void)n_in; (void)out_size; (void)ws_size;
    const float* X   = (const float*)d_in[0];
    const int*   ids = (const int*)d_in[1];
    const float* vW1 = (const float*)d_in[2];
    const float* vb1 = (const float*)d_in[3];
    const float* vW2 = (const float*)d_in[4];
    const float* vb2 = (const float*)d_in[5];
    const float* pW1 = (const float*)d_in[6];
    const float* pb1 = (const float*)d_in[7];
    const float* pW2 = (const float*)d_in[8];
    const float* pb2 = (const float*)d_in[9];
    float* out = (float*)d_out;

    // workspace: Wc 512KB ++ W2c 16KB ++ cnt[2] (256B slot) ++ idxV ++ idxP
    char* ws = (char*)d_ws;
    __hip_bfloat16* Wc  = (__hip_bfloat16*)ws;
    __hip_bfloat16* W2c = (__hip_bfloat16*)(ws + 512 * 1024);
    int* cnt  = (int*)(ws + 512 * 1024 + 16 * 1024);
    int* idxV = (int*)(ws + 512 * 1024 + 16 * 1024 + 256);
    int* idxP = idxV + TOKENS;

    hipLaunchKernelGGL(prep_kernel, dim3(132), dim3(256), 0, stream,
                       vW1, pW1, vW2, pW2, Wc, W2c, cnt);

    hipLaunchKernelGGL(compact_kernel, dim3(TOKENS / 256), dim3(256), 0, stream,
                       ids, out, cnt, idxV, idxP);

    // grid covers worst case (all tokens one type): 1024 tiles x 2 heads
    hipLaunchKernelGGL(intention_heads_kernel, dim3(2048), dim3(512), 0, stream,
                       X, cnt, idxV, idxP, Wc, W2c, vb1, pb1, vb2, pb2, out);
}